// Round 8
// baseline (366.527 us; speedup 1.0000x reference)
//
#include <hip/hip_runtime.h>
#include <hip/hip_bf16.h>

// Switch-Transformer FFN, top-1 routing. B=4,S=4096,D=1024,F=2048,E=8.
// Pipeline: router_logits(+x->bf16) | bucketize | W1/W2 transpose->bf16 |
// grouped GEMM1 (gathered A, GELU, h bf16 dense by slot) |
// grouped GEMM2 (dense A, scale epi, scatter fp32).
// GEMM: 256x256, BK=32, ring-2 double-buffer (66KB LDS -> 2 blocks/CU,
// 16 waves/CU): m97 schedule (stage-next-first, 12 ds_read, lgkm0,
// 32-MFMA cluster, vmcnt(0), barrier). Drain covered by sibling block TLP.
// 0-conflict XOR swizzle. XCD-chunked expert/tile decode.

typedef __attribute__((ext_vector_type(8))) short short8;
typedef __attribute__((ext_vector_type(4))) float f32x4;

struct __align__(8) us4 { unsigned short x, y, z, w; };

__device__ __forceinline__ void gload16(const void* g, void* l) {
  __builtin_amdgcn_global_load_lds(
      (const __attribute__((address_space(1))) unsigned int*)g,
      (__attribute__((address_space(3))) unsigned int*)l, 16, 0, 0);
}

__device__ __forceinline__ unsigned short f2b(float f) {
  union { float f; unsigned u; } v; v.f = f;
  unsigned r = v.u + 0x7FFFu + ((v.u >> 16) & 1u);   // RNE
  return (unsigned short)(r >> 16);
}

// ---------------- router: logits, softmax top-1, expert id, x->bf16 ---------
__global__ __launch_bounds__(256) void router_logits(
    const float* __restrict__ x, const float* __restrict__ Wr,
    const float* __restrict__ br, float* __restrict__ wts,
    int* __restrict__ eidx, unsigned short* __restrict__ xb)
{
  const int lane = threadIdx.x & 63;
  const int wid  = threadIdx.x >> 6;
  const int t = blockIdx.x * 4 + wid;

  const float4* x4 = (const float4*)(x + (size_t)t * 1024);
  float acc[8];
#pragma unroll
  for (int e = 0; e < 8; ++e) acc[e] = 0.f;
#pragma unroll
  for (int i = 0; i < 4; ++i) {
    float4 v = x4[lane + 64 * i];
    const int d = (lane + 64 * i) * 4;
    const float* wr = Wr + (size_t)d * 8;
    float xs[4] = {v.x, v.y, v.z, v.w};
    us4 o;
    o.x = f2b(v.x); o.y = f2b(v.y); o.z = f2b(v.z); o.w = f2b(v.w);
    *(us4*)(xb + (size_t)t * 1024 + (size_t)(lane + 64 * i) * 4) = o;
#pragma unroll
    for (int j = 0; j < 4; ++j) {
      float4 w0 = *(const float4*)(wr + j * 8);
      float4 w1 = *(const float4*)(wr + j * 8 + 4);
      acc[0] += xs[j] * w0.x; acc[1] += xs[j] * w0.y;
      acc[2] += xs[j] * w0.z; acc[3] += xs[j] * w0.w;
      acc[4] += xs[j] * w1.x; acc[5] += xs[j] * w1.y;
      acc[6] += xs[j] * w1.z; acc[7] += xs[j] * w1.w;
    }
  }
#pragma unroll
  for (int e = 0; e < 8; ++e) {
    float v = acc[e];
#pragma unroll
    for (int m = 32; m; m >>= 1) v += __shfl_xor(v, m, 64);
    acc[e] = v;
  }
  if (lane == 0) {
    float lg[8];
#pragma unroll
    for (int e = 0; e < 8; ++e) lg[e] = acc[e] + br[e];
    float mx = lg[0]; int bi = 0;
#pragma unroll
    for (int e = 1; e < 8; ++e) if (lg[e] > mx) { mx = lg[e]; bi = e; }  // first-max == argmax
    float s = 0.f;
#pragma unroll
    for (int e = 0; e < 8; ++e) s += expf(lg[e] - mx);
    wts[t]  = 1.0f / s;
    eidx[t] = bi;
  }
}

// ---------------- bucketize ----------
__global__ __launch_bounds__(256) void bucketize(
    const int* __restrict__ eidx, int* __restrict__ cnt, int* __restrict__ list)
{
  __shared__ int lcnt[8], base[8];
  const int tid = threadIdx.x;
  if (tid < 8) lcnt[tid] = 0;
  __syncthreads();
  const int t = blockIdx.x * 256 + tid;
  const int e = eidx[t];
  const int lpos = atomicAdd(&lcnt[e], 1);
  __syncthreads();
  if (tid < 8) base[tid] = atomicAdd(&cnt[tid], lcnt[tid]);
  __syncthreads();
  list[e * 16384 + base[e] + lpos] = t;
}

// ---------------- W[k][n] fp32 -> Wt[n][k] bf16 ----------
__global__ __launch_bounds__(256) void transpose_cvt(
    const float* __restrict__ W, unsigned short* __restrict__ Wt, int K, int N)
{
  __shared__ float tl[64][65];
  const int e = blockIdx.z;
  const float* Wp = W + (size_t)e * K * N;
  unsigned short* Wtp = Wt + (size_t)e * K * N;
  const int k0 = blockIdx.y * 64, n0 = blockIdx.x * 64;
  const int r = threadIdx.x >> 4, c4 = (threadIdx.x & 15) * 4;
#pragma unroll
  for (int i = 0; i < 4; ++i) {
    float4 v = *(const float4*)(Wp + (size_t)(k0 + r + i * 16) * N + n0 + c4);
    tl[r + i * 16][c4 + 0] = v.x; tl[r + i * 16][c4 + 1] = v.y;
    tl[r + i * 16][c4 + 2] = v.z; tl[r + i * 16][c4 + 3] = v.w;
  }
  __syncthreads();
#pragma unroll
  for (int i = 0; i < 4; ++i) {
    const int n = r + i * 16;
    us4 o;
    o.x = f2b(tl[c4 + 0][n]); o.y = f2b(tl[c4 + 1][n]);
    o.z = f2b(tl[c4 + 2][n]); o.w = f2b(tl[c4 + 3][n]);
    *(us4*)(Wtp + (size_t)(n0 + n) * K + k0 + c4) = o;
  }
}

// ---------------- grouped GEMM: 256x256, BK=32, ring-2, 2 blocks/CU ---------
// LDS (67584 B): A dbuf 2x16KB @0; B dbuf 2x16KB @32768; tok@65536 wt@66560.
// Swizzle (measured 0-conflict): 16B-slot c of row r holds chunk c^((r>>1)&3).
// Per subtile T: { STG(T+1 -> buf^1) | 12 ds_read frags(T, buf) | lgkmcnt(0)
//   | setprio(1) 32 MFMA setprio(0) | vmcnt(0) | s_barrier }.
// Ring-2 safety: buf^1's reads (iter T-1) completed before each wave's
// barrier T-1 arrival; stage into buf^1 happens after that barrier. vmcnt(0)
// before barrier certifies T+1 for all waves at iter T+1 top. The drain is
// covered by the co-resident block's waves (m97 mechanism).
template <int K, int N, int EPI, int LOGNB>
__global__ __launch_bounds__(512, 2) void gemm_moe8(
    const unsigned short* __restrict__ A,    // EPI1: xb[16384][K] (token rows)
                                             // EPI2: h [16384][K] (slot rows)
    const unsigned short* __restrict__ Bt,   // [8][N][K] bf16
    const float* __restrict__ bias,          // [8][N]
    const int* __restrict__ cnt, const int* __restrict__ list,
    const float* __restrict__ wts, void* __restrict__ outp)
{
  constexpr int NT = K / 32;
  constexpr int NB = 1 << LOGNB;
  extern __shared__ char lds[];
  int*   tok_s = (int*)(lds + 65536);
  float* wt_s  = (float*)(lds + 66560);

  // ---- decode: XCD-chunked p -> (expert, mb, nb); nb fast (A-panel reuse)
  const int q = gridDim.x >> 3;
  const int p = ((int)blockIdx.x & 7) * q + ((int)blockIdx.x >> 3);
  int e = -1, pre = 0, cnte = 0, loc = p;
#pragma unroll
  for (int i = 0; i < 8; ++i) {
    const int c = cnt[i];
    const int bl = ((c + 255) >> 8) << LOGNB;
    if (e < 0) {
      if (loc < bl) { e = i; cnte = c; }
      else { loc -= bl; pre += c; }
    }
  }
  if (e < 0) return;
  const int row0 = (loc >> LOGNB) << 8;
  const int n0   = (loc & (NB - 1)) << 8;

  const int tid = threadIdx.x;
  const int lane = tid & 63, wid = tid >> 6;
  const int wr = wid >> 2, wc = wid & 3;     // wave output: rows wr*128, cols wc*64
  const int l15 = lane & 15;

  if (tid < 256) {
    const int s = row0 + tid;
    if (s < cnte) {
      const int t = list[e * 16384 + s];
      tok_s[tid] = t;
      wt_s[tid]  = (EPI == 2) ? wts[t] : 0.f;
    } else { tok_s[tid] = 0; wt_s[tid] = 0.f; }
  }
  __syncthreads();

  // ---- staging: thread covers rows {srow, 128+srow}, 16B slot (tid&3)
  const int srow = tid >> 2;                 // 0..127
  const int gch  = ((tid & 3) ^ ((srow >> 1) & 3)) * 8;   // pre-swizzled chunk
  const unsigned short* aG0;
  const unsigned short* aG1;
  if (EPI == 1) {                            // gathered token rows
    aG0 = A + (size_t)tok_s[srow] * K + gch;
    aG1 = A + (size_t)tok_s[128 + srow] * K + gch;
  } else {                                   // dense slot rows
    aG0 = A + (size_t)min(pre + row0 + srow, 16383) * K + gch;
    aG1 = A + (size_t)min(pre + row0 + 128 + srow, 16383) * K + gch;
  }
  const unsigned short* bG0 = Bt + ((size_t)e * N + n0 + srow) * K + gch;
  const unsigned short* bG1 = Bt + ((size_t)e * N + n0 + 128 + srow) * K + gch;

  // ---- fragment read bases (XOR folds to per-lane constant)
  const int xo = (((lane >> 4) ^ ((l15 >> 1) & 3)) << 4);
  const char* aB = lds + wr * 8192 + l15 * 64 + xo;           // + buf*16384 + m*1024
  const char* bB = lds + 32768 + wc * 4096 + l15 * 64 + xo;   // + buf*16384 + n*1024

  f32x4 acc[8][4];
#pragma unroll
  for (int m = 0; m < 8; ++m)
#pragma unroll
    for (int n = 0; n < 4; ++n) acc[m][n] = (f32x4){0.f, 0.f, 0.f, 0.f};

#define STG_A(S, T) do { \
    char* d_ = lds + (S) * 16384 + (wid << 10); \
    gload16(aG0 + (size_t)(T) * 32, d_); \
    gload16(aG1 + (size_t)(T) * 32, d_ + 8192); } while (0)
#define STG_B(S, T) do { \
    char* d_ = lds + 32768 + (S) * 16384 + (wid << 10); \
    gload16(bG0 + (size_t)(T) * 32, d_); \
    gload16(bG1 + (size_t)(T) * 32, d_ + 8192); } while (0)

  // ---- prologue: stage tile 0 into buf 0
  STG_A(0, 0); STG_B(0, 0);
  asm volatile("s_waitcnt vmcnt(0)" ::: "memory");
  __builtin_amdgcn_s_barrier();

  short8 aF[8], bF[4];
#pragma unroll 1
  for (int T = 0; T < NT; ++T) {
    const int buf = T & 1;
    const int Ts  = (T + 1 < NT) ? T + 1 : NT - 1;   // dummy restage at tail
    // stage next tile first: loads fly under this tile's reads + MFMA
    STG_A(buf ^ 1, Ts);
    STG_B(buf ^ 1, Ts);
    const char* aT = aB + buf * 16384;
    const char* bT = bB + buf * 16384;
#pragma unroll
    for (int m = 0; m < 8; ++m) aF[m] = *(const short8*)(aT + m * 1024);
#pragma unroll
    for (int n = 0; n < 4; ++n) bF[n] = *(const short8*)(bT + n * 1024);
    asm volatile("s_waitcnt lgkmcnt(0)" ::: "memory");
    __builtin_amdgcn_sched_barrier(0);
    __builtin_amdgcn_s_setprio(1);
#pragma unroll
    for (int m = 0; m < 8; ++m)
#pragma unroll
      for (int n = 0; n < 4; ++n)
        acc[m][n] = __builtin_amdgcn_mfma_f32_16x16x32_bf16(
            aF[m], bF[n], acc[m][n], 0, 0, 0);
    __builtin_amdgcn_s_setprio(0);
    __builtin_amdgcn_sched_barrier(0);
    asm volatile("s_waitcnt vmcnt(0)" ::: "memory");   // next tile landed
    __builtin_amdgcn_s_barrier();
  }
#undef STG_A
#undef STG_B

  // ---- epilogue; C frag: col = lane&15, row = (lane>>4)*4 + r
  const int cRow0 = wr * 128 + ((lane >> 4) << 2);
  const int cColB = n0 + wc * 64 + l15;
  float bv[4];
#pragma unroll
  for (int nf = 0; nf < 4; ++nf) bv[nf] = bias[e * N + cColB + nf * 16];

  if (EPI == 1) {
    unsigned short* H = (unsigned short*)outp;
#pragma unroll
    for (int m = 0; m < 8; ++m)
#pragma unroll
      for (int r = 0; r < 4; ++r) {
        const int sl = cRow0 + m * 16 + r;
        if (row0 + sl < cnte) {
          const size_t rp = (size_t)(pre + row0 + sl) * N + cColB;
#pragma unroll
          for (int nf = 0; nf < 4; ++nf) {
            float v = acc[m][nf][r] + bv[nf];
            // tanh-form GELU via exp (dev <= ~1e-3 vs erf; threshold 3.4e-2)
            float u = 1.5957691216f * v * (1.0f + 0.044715f * v * v);
            float ex = __expf(u);
            float th = 1.0f - 2.0f / (ex + 1.0f);
            v = 0.5f * v * (1.0f + th);
            H[rp + nf * 16] = f2b(v);
          }
        }
      }
  } else {
    float* O = (float*)outp;
#pragma unroll
    for (int m = 0; m < 8; ++m)
#pragma unroll
      for (int r = 0; r < 4; ++r) {
        const int sl = cRow0 + m * 16 + r;
        if (row0 + sl < cnte) {
          const size_t rp = (size_t)tok_s[sl] * N + cColB;
          const float w = wt_s[sl];
#pragma unroll
          for (int nf = 0; nf < 4; ++nf)
            O[rp + nf * 16] = (acc[m][nf][r] + bv[nf]) * w;
        }
      }
  }
}

// ---------------------------------------------------------------------------
extern "C" void kernel_launch(void* const* d_in, const int* in_sizes, int n_in,
                              void* d_out, int out_size, void* d_ws, size_t ws_size,
                              hipStream_t stream) {
  const float* x  = (const float*)d_in[0];   // [4,4096,1024]
  const float* Wr = (const float*)d_in[1];   // [1024,8]
  const float* br = (const float*)d_in[2];   // [8]
  const float* W1 = (const float*)d_in[3];   // [8,1024,2048]
  const float* b1 = (const float*)d_in[4];   // [8,2048]
  const float* W2 = (const float*)d_in[5];   // [8,2048,1024]
  const float* b2 = (const float*)d_in[6];   // [8,1024]

  char* ws = (char*)d_ws;
  int*   cnt  = (int*)ws;                                  // 8 ints
  float* wts  = (float*)(ws + 256);                        // 16384 f32
  int*   eidx = (int*)(ws + 256 + 64 * 1024);              // 16384 int
  int*   list = (int*)(ws + 256 + 128 * 1024);             // 8*16384 int
  unsigned short* xb  = (unsigned short*)(ws + 1024 * 1024);     // 32 MB token rows
  unsigned short* w1t = xb  + (size_t)16384 * 1024;              // 32 MB
  unsigned short* w2t = w1t + (size_t)8 * 2048 * 1024;           // 32 MB
  unsigned short* h   = w2t + (size_t)8 * 1024 * 2048;           // 64 MB slot rows

  constexpr int LDS_BYTES = 67584;   // 64KB rings + tok/wt -> 2 blocks/CU
  hipFuncSetAttribute((const void*)gemm_moe8<1024, 2048, 1, 3>,
                      hipFuncAttributeMaxDynamicSharedMemorySize, LDS_BYTES);
  hipFuncSetAttribute((const void*)gemm_moe8<2048, 1024, 2, 2>,
                      hipFuncAttributeMaxDynamicSharedMemorySize, LDS_BYTES);

  hipMemsetAsync(cnt, 0, 32, stream);
  router_logits<<<dim3(4096), 256, 0, stream>>>(x, Wr, br, wts, eidx, xb);
  bucketize<<<dim3(64), 256, 0, stream>>>(eidx, cnt, list);
  transpose_cvt<<<dim3(32, 16, 8), 256, 0, stream>>>(W1, w1t, 1024, 2048);
  transpose_cvt<<<dim3(16, 32, 8), 256, 0, stream>>>(W2, w2t, 2048, 1024);
  // worst-case m-blocks: sum_e ceil(cnt_e/256) <= 64+7 = 71
  gemm_moe8<1024, 2048, 1, 3><<<dim3(71 * 8), 512, LDS_BYTES, stream>>>(
      xb, w1t, b1, cnt, list, wts, (void*)h);
  gemm_moe8<2048, 1024, 2, 2><<<dim3(71 * 4), 512, LDS_BYTES, stream>>>(
      h, w2t, b2, cnt, list, wts, d_out);
}

// Round 9
// 345.619 us; speedup vs baseline: 1.0605x; 1.0605x over previous
//
#include <hip/hip_runtime.h>
#include <hip/hip_bf16.h>

// Switch-Transformer FFN, top-1 routing. B=4,S=4096,D=1024,F=2048,E=8.
// Pipeline: router_logits(+x->bf16) | bucketize | W1/W2 transpose->bf16 |
// grouped GEMM1 (gathered A, GELU, h bf16 dense by slot) |
// grouped GEMM2 (dense A, scale epi, scatter fp32).
// GEMM: 256x128 tile (8 waves, wave 128x32, acc[8][2]=64 AGPR), BK=32,
// ring-2 dbuf, 50KB LDS + <=128 regs -> 2 blocks/CU (4 waves/SIMD): sibling
// block covers the vmcnt(0) drain (m97/m114 TLP mechanism). 2x block count
// shrinks ceil-quantization tails. 0-conflict XOR swizzle. XCD decode.

typedef __attribute__((ext_vector_type(8))) short short8;
typedef __attribute__((ext_vector_type(4))) float f32x4;

struct __align__(8) us4 { unsigned short x, y, z, w; };

__device__ __forceinline__ void gload16(const void* g, void* l) {
  __builtin_amdgcn_global_load_lds(
      (const __attribute__((address_space(1))) unsigned int*)g,
      (__attribute__((address_space(3))) unsigned int*)l, 16, 0, 0);
}

__device__ __forceinline__ unsigned short f2b(float f) {
  union { float f; unsigned u; } v; v.f = f;
  unsigned r = v.u + 0x7FFFu + ((v.u >> 16) & 1u);   // RNE
  return (unsigned short)(r >> 16);
}

// ---------------- router: logits, softmax top-1, expert id, x->bf16 ---------
__global__ __launch_bounds__(256) void router_logits(
    const float* __restrict__ x, const float* __restrict__ Wr,
    const float* __restrict__ br, float* __restrict__ wts,
    int* __restrict__ eidx, unsigned short* __restrict__ xb)
{
  const int lane = threadIdx.x & 63;
  const int wid  = threadIdx.x >> 6;
  const int t = blockIdx.x * 4 + wid;

  const float4* x4 = (const float4*)(x + (size_t)t * 1024);
  float acc[8];
#pragma unroll
  for (int e = 0; e < 8; ++e) acc[e] = 0.f;
#pragma unroll
  for (int i = 0; i < 4; ++i) {
    float4 v = x4[lane + 64 * i];
    const int d = (lane + 64 * i) * 4;
    const float* wr = Wr + (size_t)d * 8;
    float xs[4] = {v.x, v.y, v.z, v.w};
    us4 o;
    o.x = f2b(v.x); o.y = f2b(v.y); o.z = f2b(v.z); o.w = f2b(v.w);
    *(us4*)(xb + (size_t)t * 1024 + (size_t)(lane + 64 * i) * 4) = o;
#pragma unroll
    for (int j = 0; j < 4; ++j) {
      float4 w0 = *(const float4*)(wr + j * 8);
      float4 w1 = *(const float4*)(wr + j * 8 + 4);
      acc[0] += xs[j] * w0.x; acc[1] += xs[j] * w0.y;
      acc[2] += xs[j] * w0.z; acc[3] += xs[j] * w0.w;
      acc[4] += xs[j] * w1.x; acc[5] += xs[j] * w1.y;
      acc[6] += xs[j] * w1.z; acc[7] += xs[j] * w1.w;
    }
  }
#pragma unroll
  for (int e = 0; e < 8; ++e) {
    float v = acc[e];
#pragma unroll
    for (int m = 32; m; m >>= 1) v += __shfl_xor(v, m, 64);
    acc[e] = v;
  }
  if (lane == 0) {
    float lg[8];
#pragma unroll
    for (int e = 0; e < 8; ++e) lg[e] = acc[e] + br[e];
    float mx = lg[0]; int bi = 0;
#pragma unroll
    for (int e = 1; e < 8; ++e) if (lg[e] > mx) { mx = lg[e]; bi = e; }  // first-max == argmax
    float s = 0.f;
#pragma unroll
    for (int e = 0; e < 8; ++e) s += expf(lg[e] - mx);
    wts[t]  = 1.0f / s;
    eidx[t] = bi;
  }
}

// ---------------- bucketize ----------
__global__ __launch_bounds__(256) void bucketize(
    const int* __restrict__ eidx, int* __restrict__ cnt, int* __restrict__ list)
{
  __shared__ int lcnt[8], base[8];
  const int tid = threadIdx.x;
  if (tid < 8) lcnt[tid] = 0;
  __syncthreads();
  const int t = blockIdx.x * 256 + tid;
  const int e = eidx[t];
  const int lpos = atomicAdd(&lcnt[e], 1);
  __syncthreads();
  if (tid < 8) base[tid] = atomicAdd(&cnt[tid], lcnt[tid]);
  __syncthreads();
  list[e * 16384 + base[e] + lpos] = t;
}

// ---------------- W[k][n] fp32 -> Wt[n][k] bf16 ----------
__global__ __launch_bounds__(256) void transpose_cvt(
    const float* __restrict__ W, unsigned short* __restrict__ Wt, int K, int N)
{
  __shared__ float tl[64][65];
  const int e = blockIdx.z;
  const float* Wp = W + (size_t)e * K * N;
  unsigned short* Wtp = Wt + (size_t)e * K * N;
  const int k0 = blockIdx.y * 64, n0 = blockIdx.x * 64;
  const int r = threadIdx.x >> 4, c4 = (threadIdx.x & 15) * 4;
#pragma unroll
  for (int i = 0; i < 4; ++i) {
    float4 v = *(const float4*)(Wp + (size_t)(k0 + r + i * 16) * N + n0 + c4);
    tl[r + i * 16][c4 + 0] = v.x; tl[r + i * 16][c4 + 1] = v.y;
    tl[r + i * 16][c4 + 2] = v.z; tl[r + i * 16][c4 + 3] = v.w;
  }
  __syncthreads();
#pragma unroll
  for (int i = 0; i < 4; ++i) {
    const int n = r + i * 16;
    us4 o;
    o.x = f2b(tl[c4 + 0][n]); o.y = f2b(tl[c4 + 1][n]);
    o.z = f2b(tl[c4 + 2][n]); o.w = f2b(tl[c4 + 3][n]);
    *(us4*)(Wtp + (size_t)(n0 + n) * K + k0 + c4) = o;
  }
}

// ---------------- grouped GEMM: 256x128, BK=32, ring-2, 2 blocks/CU ---------
// LDS (51200 B): A dbuf 2x16KB @0; B dbuf 2x8KB @32768; tok@49152 wt@50176.
// Swizzle (measured 0-conflict): 16B-slot c of row r holds chunk c^((r>>1)&3).
// Per subtile T: { STG(T+1 -> buf^1) (3 gloads) | 10 ds_read frags(T,buf) |
//   lgkmcnt(0) | setprio(1) 16 MFMA setprio(0) | vmcnt(0) | s_barrier }.
// Drain covered by the co-resident sibling block's waves.
template <int K, int N, int EPI, int LOGNB>
__global__ __launch_bounds__(512, 4) void gemm_moe8(
    const unsigned short* __restrict__ A,    // EPI1: xb[16384][K] (token rows)
                                             // EPI2: h [16384][K] (slot rows)
    const unsigned short* __restrict__ Bt,   // [8][N][K] bf16
    const float* __restrict__ bias,          // [8][N]
    const int* __restrict__ cnt, const int* __restrict__ list,
    const float* __restrict__ wts, void* __restrict__ outp)
{
  constexpr int NT = K / 32;
  constexpr int NB = 1 << LOGNB;
  extern __shared__ char lds[];
  int*   tok_s = (int*)(lds + 49152);
  float* wt_s  = (float*)(lds + 50176);

  // ---- decode: XCD-chunked p -> (expert, mb, nb); nb fast (A-panel reuse)
  const int q = gridDim.x >> 3;
  const int p = ((int)blockIdx.x & 7) * q + ((int)blockIdx.x >> 3);
  int e = -1, pre = 0, cnte = 0, loc = p;
#pragma unroll
  for (int i = 0; i < 8; ++i) {
    const int c = cnt[i];
    const int bl = ((c + 255) >> 8) << LOGNB;
    if (e < 0) {
      if (loc < bl) { e = i; cnte = c; }
      else { loc -= bl; pre += c; }
    }
  }
  if (e < 0) return;
  const int row0 = (loc >> LOGNB) << 8;      // BM=256
  const int n0   = (loc & (NB - 1)) << 7;    // BN=128

  const int tid = threadIdx.x;
  const int lane = tid & 63, wid = tid >> 6;
  const int wr = wid >> 2, wc = wid & 3;     // wave output: rows wr*128, cols wc*32
  const int l15 = lane & 15;

  if (tid < 256) {
    const int s = row0 + tid;
    if (s < cnte) {
      const int t = list[e * 16384 + s];
      tok_s[tid] = t;
      wt_s[tid]  = (EPI == 2) ? wts[t] : 0.f;
    } else { tok_s[tid] = 0; wt_s[tid] = 0.f; }
  }
  __syncthreads();

  // ---- staging: thread covers A rows {srow, 128+srow}, B row srow
  const int srow = tid >> 2;                 // 0..127
  const int gch  = ((tid & 3) ^ ((srow >> 1) & 3)) * 8;   // pre-swizzled chunk
  const unsigned short* aG0;
  const unsigned short* aG1;
  if (EPI == 1) {                            // gathered token rows
    aG0 = A + (size_t)tok_s[srow] * K + gch;
    aG1 = A + (size_t)tok_s[128 + srow] * K + gch;
  } else {                                   // dense slot rows
    aG0 = A + (size_t)min(pre + row0 + srow, 16383) * K + gch;
    aG1 = A + (size_t)min(pre + row0 + 128 + srow, 16383) * K + gch;
  }
  const unsigned short* bG0 = Bt + ((size_t)e * N + n0 + srow) * K + gch;

  // ---- fragment read bases (XOR folds to per-lane constant)
  const int xo = (((lane >> 4) ^ ((l15 >> 1) & 3)) << 4);
  const char* aB = lds + wr * 8192 + l15 * 64 + xo;           // + buf*16384 + m*1024
  const char* bB = lds + 32768 + wc * 2048 + l15 * 64 + xo;   // + buf*8192  + n*1024

  f32x4 acc[8][2];
#pragma unroll
  for (int m = 0; m < 8; ++m)
#pragma unroll
    for (int n = 0; n < 2; ++n) acc[m][n] = (f32x4){0.f, 0.f, 0.f, 0.f};

#define STG_A(S, T) do { \
    char* d_ = lds + (S) * 16384 + (wid << 10); \
    gload16(aG0 + (size_t)(T) * 32, d_); \
    gload16(aG1 + (size_t)(T) * 32, d_ + 8192); } while (0)
#define STG_B(S, T) do { \
    char* d_ = lds + 32768 + (S) * 8192 + (wid << 10); \
    gload16(bG0 + (size_t)(T) * 32, d_); } while (0)

  // ---- prologue: stage tile 0 into buf 0
  STG_A(0, 0); STG_B(0, 0);
  asm volatile("s_waitcnt vmcnt(0)" ::: "memory");
  __builtin_amdgcn_s_barrier();

  short8 aF[8], bF[2];
#pragma unroll 1
  for (int T = 0; T < NT; ++T) {
    const int buf = T & 1;
    const int Ts  = (T + 1 < NT) ? T + 1 : NT - 1;   // dummy restage at tail
    // stage next tile first: loads fly under this tile's reads + MFMA
    STG_A(buf ^ 1, Ts);
    STG_B(buf ^ 1, Ts);
    const char* aT = aB + buf * 16384;
    const char* bT = bB + buf * 8192;
#pragma unroll
    for (int m = 0; m < 8; ++m) aF[m] = *(const short8*)(aT + m * 1024);
#pragma unroll
    for (int n = 0; n < 2; ++n) bF[n] = *(const short8*)(bT + n * 1024);
    asm volatile("s_waitcnt lgkmcnt(0)" ::: "memory");
    __builtin_amdgcn_sched_barrier(0);
    __builtin_amdgcn_s_setprio(1);
#pragma unroll
    for (int m = 0; m < 8; ++m)
#pragma unroll
      for (int n = 0; n < 2; ++n)
        acc[m][n] = __builtin_amdgcn_mfma_f32_16x16x32_bf16(
            aF[m], bF[n], acc[m][n], 0, 0, 0);
    __builtin_amdgcn_s_setprio(0);
    __builtin_amdgcn_sched_barrier(0);
    asm volatile("s_waitcnt vmcnt(0)" ::: "memory");   // next tile landed
    __builtin_amdgcn_s_barrier();
  }
#undef STG_A
#undef STG_B

  // ---- epilogue; C frag: col = lane&15, row = (lane>>4)*4 + r
  const int cRow0 = wr * 128 + ((lane >> 4) << 2);
  const int cColB = n0 + wc * 32 + l15;
  float bv[2];
#pragma unroll
  for (int nf = 0; nf < 2; ++nf) bv[nf] = bias[e * N + cColB + nf * 16];

  if (EPI == 1) {
    unsigned short* H = (unsigned short*)outp;
#pragma unroll
    for (int m = 0; m < 8; ++m)
#pragma unroll
      for (int r = 0; r < 4; ++r) {
        const int sl = cRow0 + m * 16 + r;
        if (row0 + sl < cnte) {
          const size_t rp = (size_t)(pre + row0 + sl) * N + cColB;
#pragma unroll
          for (int nf = 0; nf < 2; ++nf) {
            float v = acc[m][nf][r] + bv[nf];
            // tanh-form GELU via exp (dev <= ~1e-3 vs erf; threshold 3.4e-2)
            float u = 1.5957691216f * v * (1.0f + 0.044715f * v * v);
            float ex = __expf(u);
            float th = 1.0f - 2.0f / (ex + 1.0f);
            v = 0.5f * v * (1.0f + th);
            H[rp + nf * 16] = f2b(v);
          }
        }
      }
  } else {
    float* O = (float*)outp;
#pragma unroll
    for (int m = 0; m < 8; ++m)
#pragma unroll
      for (int r = 0; r < 4; ++r) {
        const int sl = cRow0 + m * 16 + r;
        if (row0 + sl < cnte) {
          const size_t rp = (size_t)tok_s[sl] * N + cColB;
          const float w = wt_s[sl];
#pragma unroll
          for (int nf = 0; nf < 2; ++nf)
            O[rp + nf * 16] = (acc[m][nf][r] + bv[nf]) * w;
        }
      }
  }
}

// ---------------------------------------------------------------------------
extern "C" void kernel_launch(void* const* d_in, const int* in_sizes, int n_in,
                              void* d_out, int out_size, void* d_ws, size_t ws_size,
                              hipStream_t stream) {
  const float* x  = (const float*)d_in[0];   // [4,4096,1024]
  const float* Wr = (const float*)d_in[1];   // [1024,8]
  const float* br = (const float*)d_in[2];   // [8]
  const float* W1 = (const float*)d_in[3];   // [8,1024,2048]
  const float* b1 = (const float*)d_in[4];   // [8,2048]
  const float* W2 = (const float*)d_in[5];   // [8,2048,1024]
  const float* b2 = (const float*)d_in[6];   // [8,1024]

  char* ws = (char*)d_ws;
  int*   cnt  = (int*)ws;                                  // 8 ints
  float* wts  = (float*)(ws + 256);                        // 16384 f32
  int*   eidx = (int*)(ws + 256 + 64 * 1024);              // 16384 int
  int*   list = (int*)(ws + 256 + 128 * 1024);             // 8*16384 int
  unsigned short* xb  = (unsigned short*)(ws + 1024 * 1024);     // 32 MB token rows
  unsigned short* w1t = xb  + (size_t)16384 * 1024;              // 32 MB
  unsigned short* w2t = w1t + (size_t)8 * 2048 * 1024;           // 32 MB
  unsigned short* h   = w2t + (size_t)8 * 1024 * 2048;           // 64 MB slot rows

  constexpr int LDS_BYTES = 51200;   // 48KB rings + tok/wt -> 2 blocks/CU
  hipFuncSetAttribute((const void*)gemm_moe8<1024, 2048, 1, 4>,
                      hipFuncAttributeMaxDynamicSharedMemorySize, LDS_BYTES);
  hipFuncSetAttribute((const void*)gemm_moe8<2048, 1024, 2, 3>,
                      hipFuncAttributeMaxDynamicSharedMemorySize, LDS_BYTES);

  hipMemsetAsync(cnt, 0, 32, stream);
  router_logits<<<dim3(4096), 256, 0, stream>>>(x, Wr, br, wts, eidx, xb);
  bucketize<<<dim3(64), 256, 0, stream>>>(eidx, cnt, list);
  transpose_cvt<<<dim3(32, 16, 8), 256, 0, stream>>>(W1, w1t, 1024, 2048);
  transpose_cvt<<<dim3(16, 32, 8), 256, 0, stream>>>(W2, w2t, 2048, 1024);
  // worst-case m-blocks: sum_e ceil(cnt_e/256) <= 64+7 = 71
  gemm_moe8<1024, 2048, 1, 4><<<dim3(71 * 16), 512, LDS_BYTES, stream>>>(
      xb, w1t, b1, cnt, list, wts, (void*)h);
  gemm_moe8<2048, 1024, 2, 3><<<dim3(71 * 8), 512, LDS_BYTES, stream>>>(
      h, w2t, b2, cnt, list, wts, d_out);
}

// Round 10
// 321.165 us; speedup vs baseline: 1.1412x; 1.0761x over previous
//
#include <hip/hip_runtime.h>
#include <hip/hip_bf16.h>

// Switch-Transformer FFN, top-1 routing. B=4,S=4096,D=1024,F=2048,E=8.
// Pipeline: router_logits(+x->bf16) | bucketize | W1/W2 transpose->bf16 |
// grouped GEMM1 (gathered A, GELU, h bf16 dense by slot) |
// grouped GEMM2 (dense A, scale epi, scatter fp32).
// GEMM: 256x128 tile (8 waves, wave 128x32, acc[8][2]=64 AGPR), BK=32,
// ring-3 LDS (74KB) -> 2 blocks/CU AND counted vmcnt(3) (never drains):
// 2-subtile lookahead (~2400cyc) hides HBM latency; 2 blocks/CU kills the
// ceil-quantization tail (gemm1 = 2.0 rounds, gemm2 = 1.0 round exact).
// 0-conflict XOR swizzle. XCD-chunked nb-fast decode.

typedef __attribute__((ext_vector_type(8))) short short8;
typedef __attribute__((ext_vector_type(4))) float f32x4;

struct __align__(8) us4 { unsigned short x, y, z, w; };

__device__ __forceinline__ void gload16(const void* g, void* l) {
  __builtin_amdgcn_global_load_lds(
      (const __attribute__((address_space(1))) unsigned int*)g,
      (__attribute__((address_space(3))) unsigned int*)l, 16, 0, 0);
}

__device__ __forceinline__ unsigned short f2b(float f) {
  union { float f; unsigned u; } v; v.f = f;
  unsigned r = v.u + 0x7FFFu + ((v.u >> 16) & 1u);   // RNE
  return (unsigned short)(r >> 16);
}

// ---------------- router: logits, softmax top-1, expert id, x->bf16 ---------
__global__ __launch_bounds__(256) void router_logits(
    const float* __restrict__ x, const float* __restrict__ Wr,
    const float* __restrict__ br, float* __restrict__ wts,
    int* __restrict__ eidx, unsigned short* __restrict__ xb)
{
  const int lane = threadIdx.x & 63;
  const int wid  = threadIdx.x >> 6;
  const int t = blockIdx.x * 4 + wid;

  const float4* x4 = (const float4*)(x + (size_t)t * 1024);
  float acc[8];
#pragma unroll
  for (int e = 0; e < 8; ++e) acc[e] = 0.f;
#pragma unroll
  for (int i = 0; i < 4; ++i) {
    float4 v = x4[lane + 64 * i];
    const int d = (lane + 64 * i) * 4;
    const float* wr = Wr + (size_t)d * 8;
    float xs[4] = {v.x, v.y, v.z, v.w};
    us4 o;
    o.x = f2b(v.x); o.y = f2b(v.y); o.z = f2b(v.z); o.w = f2b(v.w);
    *(us4*)(xb + (size_t)t * 1024 + (size_t)(lane + 64 * i) * 4) = o;
#pragma unroll
    for (int j = 0; j < 4; ++j) {
      float4 w0 = *(const float4*)(wr + j * 8);
      float4 w1 = *(const float4*)(wr + j * 8 + 4);
      acc[0] += xs[j] * w0.x; acc[1] += xs[j] * w0.y;
      acc[2] += xs[j] * w0.z; acc[3] += xs[j] * w0.w;
      acc[4] += xs[j] * w1.x; acc[5] += xs[j] * w1.y;
      acc[6] += xs[j] * w1.z; acc[7] += xs[j] * w1.w;
    }
  }
#pragma unroll
  for (int e = 0; e < 8; ++e) {
    float v = acc[e];
#pragma unroll
    for (int m = 32; m; m >>= 1) v += __shfl_xor(v, m, 64);
    acc[e] = v;
  }
  if (lane == 0) {
    float lg[8];
#pragma unroll
    for (int e = 0; e < 8; ++e) lg[e] = acc[e] + br[e];
    float mx = lg[0]; int bi = 0;
#pragma unroll
    for (int e = 1; e < 8; ++e) if (lg[e] > mx) { mx = lg[e]; bi = e; }  // first-max == argmax
    float s = 0.f;
#pragma unroll
    for (int e = 0; e < 8; ++e) s += expf(lg[e] - mx);
    wts[t]  = 1.0f / s;
    eidx[t] = bi;
  }
}

// ---------------- bucketize ----------
__global__ __launch_bounds__(256) void bucketize(
    const int* __restrict__ eidx, int* __restrict__ cnt, int* __restrict__ list)
{
  __shared__ int lcnt[8], base[8];
  const int tid = threadIdx.x;
  if (tid < 8) lcnt[tid] = 0;
  __syncthreads();
  const int t = blockIdx.x * 256 + tid;
  const int e = eidx[t];
  const int lpos = atomicAdd(&lcnt[e], 1);
  __syncthreads();
  if (tid < 8) base[tid] = atomicAdd(&cnt[tid], lcnt[tid]);
  __syncthreads();
  list[e * 16384 + base[e] + lpos] = t;
}

// ---------------- W[k][n] fp32 -> Wt[n][k] bf16 ----------
__global__ __launch_bounds__(256) void transpose_cvt(
    const float* __restrict__ W, unsigned short* __restrict__ Wt, int K, int N)
{
  __shared__ float tl[64][65];
  const int e = blockIdx.z;
  const float* Wp = W + (size_t)e * K * N;
  unsigned short* Wtp = Wt + (size_t)e * K * N;
  const int k0 = blockIdx.y * 64, n0 = blockIdx.x * 64;
  const int r = threadIdx.x >> 4, c4 = (threadIdx.x & 15) * 4;
#pragma unroll
  for (int i = 0; i < 4; ++i) {
    float4 v = *(const float4*)(Wp + (size_t)(k0 + r + i * 16) * N + n0 + c4);
    tl[r + i * 16][c4 + 0] = v.x; tl[r + i * 16][c4 + 1] = v.y;
    tl[r + i * 16][c4 + 2] = v.z; tl[r + i * 16][c4 + 3] = v.w;
  }
  __syncthreads();
#pragma unroll
  for (int i = 0; i < 4; ++i) {
    const int n = r + i * 16;
    us4 o;
    o.x = f2b(tl[c4 + 0][n]); o.y = f2b(tl[c4 + 1][n]);
    o.z = f2b(tl[c4 + 2][n]); o.w = f2b(tl[c4 + 3][n]);
    *(us4*)(Wtp + (size_t)(n0 + n) * K + k0 + c4) = o;
  }
}

// ---------------- grouped GEMM: 256x128, BK=32, ring-3, 2 blocks/CU ---------
// LDS (75776 B): A slots 3x16KB @0; B slots 3x8KB @49152; tok@73728 wt@74752.
// Swizzle (measured 0-conflict): 16B-slot c of row r holds chunk c^((r>>1)&3).
// Iter T (slot SR=T%3, stage slot SS=(T+2)%3, compile-time via x3 unroll):
//   { STG A+B(tile T+2 -> SS) (3 gloads) | 10 ds_read frags(T, SR) |
//     lgkmcnt(0) | setprio(1) 16 MFMA setprio(0) | vmcnt(3) | s_barrier }.
// vmcnt(3): outstanding = tiles T+1,T+2 (6 loads) -> wait completes tile T+1
// (certified for iter T+1 after barrier). Never drains to 0 in-loop.
// Slot safety: write slot (T+2)%3 == read slot of iter T-1; those reads
// complete before the T-1 barrier (lgkm0 precedes MFMA precedes barrier).
template <int K, int N, int EPI, int LOGNB>
__global__ __launch_bounds__(512, 4) void gemm_moe8(
    const unsigned short* __restrict__ A,    // EPI1: xb[16384][K] (token rows)
                                             // EPI2: h [16384][K] (slot rows)
    const unsigned short* __restrict__ Bt,   // [8][N][K] bf16
    const float* __restrict__ bias,          // [8][N]
    const int* __restrict__ cnt, const int* __restrict__ list,
    const float* __restrict__ wts, void* __restrict__ outp)
{
  constexpr int NT = K / 32;
  constexpr int NB = 1 << LOGNB;
  extern __shared__ char lds[];
  int*   tok_s = (int*)(lds + 73728);
  float* wt_s  = (float*)(lds + 74752);

  // ---- decode: XCD-chunked p -> (expert, mb, nb); nb fast (A-panel reuse)
  const int q = gridDim.x >> 3;
  const int p = ((int)blockIdx.x & 7) * q + ((int)blockIdx.x >> 3);
  int e = -1, pre = 0, cnte = 0, loc = p;
#pragma unroll
  for (int i = 0; i < 8; ++i) {
    const int c = cnt[i];
    const int bl = ((c + 255) >> 8) << LOGNB;
    if (e < 0) {
      if (loc < bl) { e = i; cnte = c; }
      else { loc -= bl; pre += c; }
    }
  }
  if (e < 0) return;
  const int row0 = (loc >> LOGNB) << 8;      // BM=256
  const int n0   = (loc & (NB - 1)) << 7;    // BN=128

  const int tid = threadIdx.x;
  const int lane = tid & 63, wid = tid >> 6;
  const int wr = wid >> 2, wc = wid & 3;     // wave output: rows wr*128, cols wc*32
  const int l15 = lane & 15;

  if (tid < 256) {
    const int s = row0 + tid;
    if (s < cnte) {
      const int t = list[e * 16384 + s];
      tok_s[tid] = t;
      wt_s[tid]  = (EPI == 2) ? wts[t] : 0.f;
    } else { tok_s[tid] = 0; wt_s[tid] = 0.f; }
  }
  __syncthreads();

  // ---- staging: thread covers A rows {srow, 128+srow}, B row srow
  const int srow = tid >> 2;                 // 0..127
  const int gch  = ((tid & 3) ^ ((srow >> 1) & 3)) * 8;   // pre-swizzled chunk
  const unsigned short* aG0;
  const unsigned short* aG1;
  if (EPI == 1) {                            // gathered token rows
    aG0 = A + (size_t)tok_s[srow] * K + gch;
    aG1 = A + (size_t)tok_s[128 + srow] * K + gch;
  } else {                                   // dense slot rows
    aG0 = A + (size_t)min(pre + row0 + srow, 16383) * K + gch;
    aG1 = A + (size_t)min(pre + row0 + 128 + srow, 16383) * K + gch;
  }
  const unsigned short* bG0 = Bt + ((size_t)e * N + n0 + srow) * K + gch;

  // ---- fragment read bases (XOR folds to per-lane constant)
  const int xo = (((lane >> 4) ^ ((l15 >> 1) & 3)) << 4);
  const char* aB = lds + wr * 8192 + l15 * 64 + xo;           // + slot*16384 + m*1024
  const char* bB = lds + 49152 + wc * 2048 + l15 * 64 + xo;   // + slot*8192  + n*1024

  f32x4 acc[8][2];
#pragma unroll
  for (int m = 0; m < 8; ++m)
#pragma unroll
    for (int n = 0; n < 2; ++n) acc[m][n] = (f32x4){0.f, 0.f, 0.f, 0.f};

#define STG_A(S, T) do { \
    char* d_ = lds + (S) * 16384 + (wid << 10); \
    gload16(aG0 + (size_t)(T) * 32, d_); \
    gload16(aG1 + (size_t)(T) * 32, d_ + 8192); } while (0)
#define STG_B(S, T) do { \
    char* d_ = lds + 49152 + (S) * 8192 + (wid << 10); \
    gload16(bG0 + (size_t)(T) * 32, d_); } while (0)

  // one subtile: read slot SR (tile T), stage tile T+2 into slot SS
#define TILE_BODY(T, SR, SS) do { \
    const int Ts_ = ((T) + 2 < NT) ? (T) + 2 : NT - 1;   /* dummy at tail */ \
    STG_A(SS, Ts_); \
    STG_B(SS, Ts_); \
    const char* aT = aB + (SR) * 16384; \
    const char* bT = bB + (SR) * 8192; \
    short8 aF[8], bF[2]; \
    _Pragma("unroll") \
    for (int m_ = 0; m_ < 8; ++m_) aF[m_] = *(const short8*)(aT + m_ * 1024); \
    _Pragma("unroll") \
    for (int n_ = 0; n_ < 2; ++n_) bF[n_] = *(const short8*)(bT + n_ * 1024); \
    asm volatile("s_waitcnt lgkmcnt(0)" ::: "memory"); \
    __builtin_amdgcn_sched_barrier(0); \
    __builtin_amdgcn_s_setprio(1); \
    _Pragma("unroll") \
    for (int m_ = 0; m_ < 8; ++m_) \
      _Pragma("unroll") \
      for (int n_ = 0; n_ < 2; ++n_) \
        acc[m_][n_] = __builtin_amdgcn_mfma_f32_16x16x32_bf16( \
            aF[m_], bF[n_], acc[m_][n_], 0, 0, 0); \
    __builtin_amdgcn_s_setprio(0); \
    __builtin_amdgcn_sched_barrier(0); \
    asm volatile("s_waitcnt vmcnt(3)" ::: "memory");   /* certify tile T+1 */ \
    __builtin_amdgcn_s_barrier(); \
  } while (0)

  // ---- prologue: stage tiles 0,1 into slots 0,1; certify tile 0
  STG_A(0, 0); STG_B(0, 0);
  STG_A(1, 1); STG_B(1, 1);
  asm volatile("s_waitcnt vmcnt(3)" ::: "memory");   // tile 0 landed
  __builtin_amdgcn_s_barrier();

#pragma unroll 1
  for (int T = 0; T < NT; T += 3) {                  // slots compile-time
    TILE_BODY(T, 0, 2);
    if (T + 1 < NT) TILE_BODY(T + 1, 1, 0);
    if (T + 2 < NT) TILE_BODY(T + 2, 2, 1);
  }
#undef TILE_BODY
#undef STG_A
#undef STG_B
  asm volatile("s_waitcnt vmcnt(0)" ::: "memory");   // drain dummy stages

  // ---- epilogue; C frag: col = lane&15, row = (lane>>4)*4 + r
  const int cRow0 = wr * 128 + ((lane >> 4) << 2);
  const int cColB = n0 + wc * 32 + l15;
  float bv[2];
#pragma unroll
  for (int nf = 0; nf < 2; ++nf) bv[nf] = bias[e * N + cColB + nf * 16];

  if (EPI == 1) {
    unsigned short* H = (unsigned short*)outp;
#pragma unroll
    for (int m = 0; m < 8; ++m)
#pragma unroll
      for (int r = 0; r < 4; ++r) {
        const int sl = cRow0 + m * 16 + r;
        if (row0 + sl < cnte) {
          const size_t rp = (size_t)(pre + row0 + sl) * N + cColB;
#pragma unroll
          for (int nf = 0; nf < 2; ++nf) {
            float v = acc[m][nf][r] + bv[nf];
            // tanh-form GELU via exp (dev <= ~1e-3 vs erf; threshold 3.4e-2)
            float u = 1.5957691216f * v * (1.0f + 0.044715f * v * v);
            float ex = __expf(u);
            float th = 1.0f - 2.0f / (ex + 1.0f);
            v = 0.5f * v * (1.0f + th);
            H[rp + nf * 16] = f2b(v);
          }
        }
      }
  } else {
    float* O = (float*)outp;
#pragma unroll
    for (int m = 0; m < 8; ++m)
#pragma unroll
      for (int r = 0; r < 4; ++r) {
        const int sl = cRow0 + m * 16 + r;
        if (row0 + sl < cnte) {
          const size_t rp = (size_t)tok_s[sl] * N + cColB;
          const float w = wt_s[sl];
#pragma unroll
          for (int nf = 0; nf < 2; ++nf)
            O[rp + nf * 16] = (acc[m][nf][r] + bv[nf]) * w;
        }
      }
  }
}

// ---------------------------------------------------------------------------
extern "C" void kernel_launch(void* const* d_in, const int* in_sizes, int n_in,
                              void* d_out, int out_size, void* d_ws, size_t ws_size,
                              hipStream_t stream) {
  const float* x  = (const float*)d_in[0];   // [4,4096,1024]
  const float* Wr = (const float*)d_in[1];   // [1024,8]
  const float* br = (const float*)d_in[2];   // [8]
  const float* W1 = (const float*)d_in[3];   // [8,1024,2048]
  const float* b1 = (const float*)d_in[4];   // [8,2048]
  const float* W2 = (const float*)d_in[5];   // [8,2048,1024]
  const float* b2 = (const float*)d_in[6];   // [8,1024]

  char* ws = (char*)d_ws;
  int*   cnt  = (int*)ws;                                  // 8 ints
  float* wts  = (float*)(ws + 256);                        // 16384 f32
  int*   eidx = (int*)(ws + 256 + 64 * 1024);              // 16384 int
  int*   list = (int*)(ws + 256 + 128 * 1024);             // 8*16384 int
  unsigned short* xb  = (unsigned short*)(ws + 1024 * 1024);     // 32 MB token rows
  unsigned short* w1t = xb  + (size_t)16384 * 1024;              // 32 MB
  unsigned short* w2t = w1t + (size_t)8 * 2048 * 1024;           // 32 MB
  unsigned short* h   = w2t + (size_t)8 * 1024 * 2048;           // 64 MB slot rows

  constexpr int LDS_BYTES = 75776;   // ring-3 + tok/wt -> 2 blocks/CU
  hipFuncSetAttribute((const void*)gemm_moe8<1024, 2048, 1, 4>,
                      hipFuncAttributeMaxDynamicSharedMemorySize, LDS_BYTES);
  hipFuncSetAttribute((const void*)gemm_moe8<2048, 1024, 2, 3>,
                      hipFuncAttributeMaxDynamicSharedMemorySize, LDS_BYTES);

  hipMemsetAsync(cnt, 0, 32, stream);
  router_logits<<<dim3(4096), 256, 0, stream>>>(x, Wr, br, wts, eidx, xb);
  bucketize<<<dim3(64), 256, 0, stream>>>(eidx, cnt, list);
  transpose_cvt<<<dim3(32, 16, 8), 256, 0, stream>>>(W1, w1t, 1024, 2048);
  transpose_cvt<<<dim3(16, 32, 8), 256, 0, stream>>>(W2, w2t, 2048, 1024);
  // worst-case m-blocks: sum_e ceil(cnt_e/256) <= 64+7 = 71
  gemm_moe8<1024, 2048, 1, 4><<<dim3(71 * 16), 512, LDS_BYTES, stream>>>(
      xb, w1t, b1, cnt, list, wts, (void*)h);
  gemm_moe8<2048, 1024, 2, 3><<<dim3(71 * 8), 512, LDS_BYTES, stream>>>(
      h, w2t, b2, cnt, list, wts, d_out);
}

// Round 11
// 320.162 us; speedup vs baseline: 1.1448x; 1.0031x over previous
//
#include <hip/hip_runtime.h>
#include <hip/hip_bf16.h>

// Switch-Transformer FFN, top-1 routing. B=4,S=4096,D=1024,F=2048,E=8.
// Pipeline: router_logits(+x->bf16) | bucketize | W1/W2 transpose->bf16 |
// grouped GEMM1 (gathered A, GELU, h bf16 dense by slot) |
// grouped GEMM2 (dense A, scale epi, scatter fp32).
// GEMM: 256x128 tile (8 waves, wave 128x32), BK=32, ring-3 LDS, counted
// vmcnt(3), 2 blocks/CU. THIS ROUND: no forced lgkmcnt(0)/sched_barrier --
// compiler emits fine-grained counted lgkmcnt so ds_reads drain UNDER the
// MFMA cluster (m97 behavior). Post-barrier compiler fences stop upward
// hoist of ds_reads across s_barrier (cross-wave staging visibility).

typedef __attribute__((ext_vector_type(8))) short short8;
typedef __attribute__((ext_vector_type(4))) float f32x4;

struct __align__(8) us4 { unsigned short x, y, z, w; };

__device__ __forceinline__ void gload16(const void* g, void* l) {
  __builtin_amdgcn_global_load_lds(
      (const __attribute__((address_space(1))) unsigned int*)g,
      (__attribute__((address_space(3))) unsigned int*)l, 16, 0, 0);
}

__device__ __forceinline__ unsigned short f2b(float f) {
  union { float f; unsigned u; } v; v.f = f;
  unsigned r = v.u + 0x7FFFu + ((v.u >> 16) & 1u);   // RNE
  return (unsigned short)(r >> 16);
}

// ---------------- router: logits, softmax top-1, expert id, x->bf16 ---------
__global__ __launch_bounds__(256) void router_logits(
    const float* __restrict__ x, const float* __restrict__ Wr,
    const float* __restrict__ br, float* __restrict__ wts,
    int* __restrict__ eidx, unsigned short* __restrict__ xb)
{
  const int lane = threadIdx.x & 63;
  const int wid  = threadIdx.x >> 6;
  const int t = blockIdx.x * 4 + wid;

  const float4* x4 = (const float4*)(x + (size_t)t * 1024);
  float acc[8];
#pragma unroll
  for (int e = 0; e < 8; ++e) acc[e] = 0.f;
#pragma unroll
  for (int i = 0; i < 4; ++i) {
    float4 v = x4[lane + 64 * i];
    const int d = (lane + 64 * i) * 4;
    const float* wr = Wr + (size_t)d * 8;
    float xs[4] = {v.x, v.y, v.z, v.w};
    us4 o;
    o.x = f2b(v.x); o.y = f2b(v.y); o.z = f2b(v.z); o.w = f2b(v.w);
    *(us4*)(xb + (size_t)t * 1024 + (size_t)(lane + 64 * i) * 4) = o;
#pragma unroll
    for (int j = 0; j < 4; ++j) {
      float4 w0 = *(const float4*)(wr + j * 8);
      float4 w1 = *(const float4*)(wr + j * 8 + 4);
      acc[0] += xs[j] * w0.x; acc[1] += xs[j] * w0.y;
      acc[2] += xs[j] * w0.z; acc[3] += xs[j] * w0.w;
      acc[4] += xs[j] * w1.x; acc[5] += xs[j] * w1.y;
      acc[6] += xs[j] * w1.z; acc[7] += xs[j] * w1.w;
    }
  }
#pragma unroll
  for (int e = 0; e < 8; ++e) {
    float v = acc[e];
#pragma unroll
    for (int m = 32; m; m >>= 1) v += __shfl_xor(v, m, 64);
    acc[e] = v;
  }
  if (lane == 0) {
    float lg[8];
#pragma unroll
    for (int e = 0; e < 8; ++e) lg[e] = acc[e] + br[e];
    float mx = lg[0]; int bi = 0;
#pragma unroll
    for (int e = 1; e < 8; ++e) if (lg[e] > mx) { mx = lg[e]; bi = e; }  // first-max == argmax
    float s = 0.f;
#pragma unroll
    for (int e = 0; e < 8; ++e) s += expf(lg[e] - mx);
    wts[t]  = 1.0f / s;
    eidx[t] = bi;
  }
}

// ---------------- bucketize ----------
__global__ __launch_bounds__(256) void bucketize(
    const int* __restrict__ eidx, int* __restrict__ cnt, int* __restrict__ list)
{
  __shared__ int lcnt[8], base[8];
  const int tid = threadIdx.x;
  if (tid < 8) lcnt[tid] = 0;
  __syncthreads();
  const int t = blockIdx.x * 256 + tid;
  const int e = eidx[t];
  const int lpos = atomicAdd(&lcnt[e], 1);
  __syncthreads();
  if (tid < 8) base[tid] = atomicAdd(&cnt[tid], lcnt[tid]);
  __syncthreads();
  list[e * 16384 + base[e] + lpos] = t;
}

// ---------------- W[k][n] fp32 -> Wt[n][k] bf16 ----------
__global__ __launch_bounds__(256) void transpose_cvt(
    const float* __restrict__ W, unsigned short* __restrict__ Wt, int K, int N)
{
  __shared__ float tl[64][65];
  const int e = blockIdx.z;
  const float* Wp = W + (size_t)e * K * N;
  unsigned short* Wtp = Wt + (size_t)e * K * N;
  const int k0 = blockIdx.y * 64, n0 = blockIdx.x * 64;
  const int r = threadIdx.x >> 4, c4 = (threadIdx.x & 15) * 4;
#pragma unroll
  for (int i = 0; i < 4; ++i) {
    float4 v = *(const float4*)(Wp + (size_t)(k0 + r + i * 16) * N + n0 + c4);
    tl[r + i * 16][c4 + 0] = v.x; tl[r + i * 16][c4 + 1] = v.y;
    tl[r + i * 16][c4 + 2] = v.z; tl[r + i * 16][c4 + 3] = v.w;
  }
  __syncthreads();
#pragma unroll
  for (int i = 0; i < 4; ++i) {
    const int n = r + i * 16;
    us4 o;
    o.x = f2b(tl[c4 + 0][n]); o.y = f2b(tl[c4 + 1][n]);
    o.z = f2b(tl[c4 + 2][n]); o.w = f2b(tl[c4 + 3][n]);
    *(us4*)(Wtp + (size_t)(n0 + n) * K + k0 + c4) = o;
  }
}

// ---------------- grouped GEMM: 256x128, BK=32, ring-3, 2 blocks/CU ---------
// LDS (75776 B): A slots 3x16KB @0; B slots 3x8KB @49152; tok@73728 wt@74752.
// Swizzle (measured 0-conflict): 16B-slot c of row r holds chunk c^((r>>1)&3).
// Iter T (slot SR=T%3, stage slot SS=(T+2)%3, compile-time via x3 unroll):
//   { STG A+B(tile T+2 -> SS) | 10 ds_read frags(T, SR) | setprio(1)
//     16 MFMA (compiler inserts counted lgkmcnt: reads drain under MFMAs)
//     setprio(0) | vmcnt(3) | s_barrier | compiler-fence }.
// vmcnt(3): outstanding = tiles T+1,T+2 (6 loads) -> certifies tile T+1.
// Post-barrier asm(""::: "memory") stops ds_read hoist above the barrier
// (cross-wave staging only visible after ALL waves' vmcnt+barrier).
template <int K, int N, int EPI, int LOGNB>
__global__ __launch_bounds__(512, 4) void gemm_moe8(
    const unsigned short* __restrict__ A,    // EPI1: xb[16384][K] (token rows)
                                             // EPI2: h [16384][K] (slot rows)
    const unsigned short* __restrict__ Bt,   // [8][N][K] bf16
    const float* __restrict__ bias,          // [8][N]
    const int* __restrict__ cnt, const int* __restrict__ list,
    const float* __restrict__ wts, void* __restrict__ outp)
{
  constexpr int NT = K / 32;
  constexpr int NB = 1 << LOGNB;
  extern __shared__ char lds[];
  int*   tok_s = (int*)(lds + 73728);
  float* wt_s  = (float*)(lds + 74752);

  // ---- decode: XCD-chunked p -> (expert, mb, nb); nb fast (A-panel reuse)
  const int q = gridDim.x >> 3;
  const int p = ((int)blockIdx.x & 7) * q + ((int)blockIdx.x >> 3);
  int e = -1, pre = 0, cnte = 0, loc = p;
#pragma unroll
  for (int i = 0; i < 8; ++i) {
    const int c = cnt[i];
    const int bl = ((c + 255) >> 8) << LOGNB;
    if (e < 0) {
      if (loc < bl) { e = i; cnte = c; }
      else { loc -= bl; pre += c; }
    }
  }
  if (e < 0) return;
  const int row0 = (loc >> LOGNB) << 8;      // BM=256
  const int n0   = (loc & (NB - 1)) << 7;    // BN=128

  const int tid = threadIdx.x;
  const int lane = tid & 63, wid = tid >> 6;
  const int wr = wid >> 2, wc = wid & 3;     // wave output: rows wr*128, cols wc*32
  const int l15 = lane & 15;

  if (tid < 256) {
    const int s = row0 + tid;
    if (s < cnte) {
      const int t = list[e * 16384 + s];
      tok_s[tid] = t;
      wt_s[tid]  = (EPI == 2) ? wts[t] : 0.f;
    } else { tok_s[tid] = 0; wt_s[tid] = 0.f; }
  }
  __syncthreads();

  // ---- staging: thread covers A rows {srow, 128+srow}, B row srow
  const int srow = tid >> 2;                 // 0..127
  const int gch  = ((tid & 3) ^ ((srow >> 1) & 3)) * 8;   // pre-swizzled chunk
  const unsigned short* aG0;
  const unsigned short* aG1;
  if (EPI == 1) {                            // gathered token rows
    aG0 = A + (size_t)tok_s[srow] * K + gch;
    aG1 = A + (size_t)tok_s[128 + srow] * K + gch;
  } else {                                   // dense slot rows
    aG0 = A + (size_t)min(pre + row0 + srow, 16383) * K + gch;
    aG1 = A + (size_t)min(pre + row0 + 128 + srow, 16383) * K + gch;
  }
  const unsigned short* bG0 = Bt + ((size_t)e * N + n0 + srow) * K + gch;

  // ---- fragment read bases (XOR folds to per-lane constant)
  const int xo = (((lane >> 4) ^ ((l15 >> 1) & 3)) << 4);
  const char* aB = lds + wr * 8192 + l15 * 64 + xo;           // + slot*16384 + m*1024
  const char* bB = lds + 49152 + wc * 2048 + l15 * 64 + xo;   // + slot*8192  + n*1024

  f32x4 acc[8][2];
#pragma unroll
  for (int m = 0; m < 8; ++m)
#pragma unroll
    for (int n = 0; n < 2; ++n) acc[m][n] = (f32x4){0.f, 0.f, 0.f, 0.f};

#define STG_A(S, T) do { \
    char* d_ = lds + (S) * 16384 + (wid << 10); \
    gload16(aG0 + (size_t)(T) * 32, d_); \
    gload16(aG1 + (size_t)(T) * 32, d_ + 8192); } while (0)
#define STG_B(S, T) do { \
    char* d_ = lds + 49152 + (S) * 8192 + (wid << 10); \
    gload16(bG0 + (size_t)(T) * 32, d_); } while (0)

  // one subtile: stage tile T+2 into SS, read slot SR, MFMA (compiler-
  // scheduled counted lgkmcnt), counted vmcnt(3), barrier, compiler fence.
#define TILE_BODY(T, SR, SS) do { \
    const int Ts_ = ((T) + 2 < NT) ? (T) + 2 : NT - 1;   /* dummy at tail */ \
    STG_A(SS, Ts_); \
    STG_B(SS, Ts_); \
    const char* aT = aB + (SR) * 16384; \
    const char* bT = bB + (SR) * 8192; \
    short8 aF[8], bF[2]; \
    _Pragma("unroll") \
    for (int m_ = 0; m_ < 8; ++m_) aF[m_] = *(const short8*)(aT + m_ * 1024); \
    _Pragma("unroll") \
    for (int n_ = 0; n_ < 2; ++n_) bF[n_] = *(const short8*)(bT + n_ * 1024); \
    __builtin_amdgcn_s_setprio(1); \
    _Pragma("unroll") \
    for (int m_ = 0; m_ < 8; ++m_) \
      _Pragma("unroll") \
      for (int n_ = 0; n_ < 2; ++n_) \
        acc[m_][n_] = __builtin_amdgcn_mfma_f32_16x16x32_bf16( \
            aF[m_], bF[n_], acc[m_][n_], 0, 0, 0); \
    __builtin_amdgcn_s_setprio(0); \
    asm volatile("s_waitcnt vmcnt(3)" ::: "memory");   /* certify tile T+1 */ \
    __builtin_amdgcn_s_barrier(); \
    asm volatile("" ::: "memory");   /* no ds_read hoists above barrier */ \
  } while (0)

  // ---- prologue: stage tiles 0,1 into slots 0,1; certify tile 0
  STG_A(0, 0); STG_B(0, 0);
  STG_A(1, 1); STG_B(1, 1);
  asm volatile("s_waitcnt vmcnt(3)" ::: "memory");   // tile 0 landed
  __builtin_amdgcn_s_barrier();
  asm volatile("" ::: "memory");

#pragma unroll 1
  for (int T = 0; T < NT; T += 3) {                  // slots compile-time
    TILE_BODY(T, 0, 2);
    if (T + 1 < NT) TILE_BODY(T + 1, 1, 0);
    if (T + 2 < NT) TILE_BODY(T + 2, 2, 1);
  }
#undef TILE_BODY
#undef STG_A
#undef STG_B
  asm volatile("s_waitcnt vmcnt(0)" ::: "memory");   // drain dummy stages

  // ---- epilogue; C frag: col = lane&15, row = (lane>>4)*4 + r
  const int cRow0 = wr * 128 + ((lane >> 4) << 2);
  const int cColB = n0 + wc * 32 + l15;
  float bv[2];
#pragma unroll
  for (int nf = 0; nf < 2; ++nf) bv[nf] = bias[e * N + cColB + nf * 16];

  if (EPI == 1) {
    unsigned short* H = (unsigned short*)outp;
#pragma unroll
    for (int m = 0; m < 8; ++m)
#pragma unroll
      for (int r = 0; r < 4; ++r) {
        const int sl = cRow0 + m * 16 + r;
        if (row0 + sl < cnte) {
          const size_t rp = (size_t)(pre + row0 + sl) * N + cColB;
#pragma unroll
          for (int nf = 0; nf < 2; ++nf) {
            float v = acc[m][nf][r] + bv[nf];
            // tanh-form GELU via exp (dev <= ~1e-3 vs erf; threshold 3.4e-2)
            float u = 1.5957691216f * v * (1.0f + 0.044715f * v * v);
            float ex = __expf(u);
            float th = 1.0f - 2.0f / (ex + 1.0f);
            v = 0.5f * v * (1.0f + th);
            H[rp + nf * 16] = f2b(v);
          }
        }
      }
  } else {
    float* O = (float*)outp;
#pragma unroll
    for (int m = 0; m < 8; ++m)
#pragma unroll
      for (int r = 0; r < 4; ++r) {
        const int sl = cRow0 + m * 16 + r;
        if (row0 + sl < cnte) {
          const size_t rp = (size_t)tok_s[sl] * N + cColB;
          const float w = wt_s[sl];
#pragma unroll
          for (int nf = 0; nf < 2; ++nf)
            O[rp + nf * 16] = (acc[m][nf][r] + bv[nf]) * w;
        }
      }
  }
}

// ---------------------------------------------------------------------------
extern "C" void kernel_launch(void* const* d_in, const int* in_sizes, int n_in,
                              void* d_out, int out_size, void* d_ws, size_t ws_size,
                              hipStream_t stream) {
  const float* x  = (const float*)d_in[0];   // [4,4096,1024]
  const float* Wr = (const float*)d_in[1];   // [1024,8]
  const float* br = (const float*)d_in[2];   // [8]
  const float* W1 = (const float*)d_in[3];   // [8,1024,2048]
  const float* b1 = (const float*)d_in[4];   // [8,2048]
  const float* W2 = (const float*)d_in[5];   // [8,2048,1024]
  const float* b2 = (const float*)d_in[6];   // [8,1024]

  char* ws = (char*)d_ws;
  int*   cnt  = (int*)ws;                                  // 8 ints
  float* wts  = (float*)(ws + 256);                        // 16384 f32
  int*   eidx = (int*)(ws + 256 + 64 * 1024);              // 16384 int
  int*   list = (int*)(ws + 256 + 128 * 1024);             // 8*16384 int
  unsigned short* xb  = (unsigned short*)(ws + 1024 * 1024);     // 32 MB token rows
  unsigned short* w1t = xb  + (size_t)16384 * 1024;              // 32 MB
  unsigned short* w2t = w1t + (size_t)8 * 2048 * 1024;           // 32 MB
  unsigned short* h   = w2t + (size_t)8 * 1024 * 2048;           // 64 MB slot rows

  constexpr int LDS_BYTES = 75776;   // ring-3 + tok/wt -> 2 blocks/CU
  hipFuncSetAttribute((const void*)gemm_moe8<1024, 2048, 1, 4>,
                      hipFuncAttributeMaxDynamicSharedMemorySize, LDS_BYTES);
  hipFuncSetAttribute((const void*)gemm_moe8<2048, 1024, 2, 3>,
                      hipFuncAttributeMaxDynamicSharedMemorySize, LDS_BYTES);

  hipMemsetAsync(cnt, 0, 32, stream);
  router_logits<<<dim3(4096), 256, 0, stream>>>(x, Wr, br, wts, eidx, xb);
  bucketize<<<dim3(64), 256, 0, stream>>>(eidx, cnt, list);
  transpose_cvt<<<dim3(32, 16, 8), 256, 0, stream>>>(W1, w1t, 1024, 2048);
  transpose_cvt<<<dim3(16, 32, 8), 256, 0, stream>>>(W2, w2t, 2048, 1024);
  // worst-case m-blocks: sum_e ceil(cnt_e/256) <= 64+7 = 71
  gemm_moe8<1024, 2048, 1, 4><<<dim3(71 * 16), 512, LDS_BYTES, stream>>>(
      xb, w1t, b1, cnt, list, wts, (void*)h);
  gemm_moe8<2048, 1024, 2, 3><<<dim3(71 * 8), 512, LDS_BYTES, stream>>>(
      h, w2t, b2, cnt, list, wts, d_out);
}